// Round 1
// baseline (79.955 us; speedup 1.0000x reference)
//
#include <hip/hip_runtime.h>
#include <hip/hip_bf16.h>
#include <math.h>

#define NSAMP 1024
#define F 256
#define E 128
#define SEQ 257
#define NH 4
#define DK 32

// ws float offsets
#define OFF_MASK   0      // 257
#define OFF_A      512    // 1024  a[k*4+h], already scaled by 1/sqrt(32)
#define OFF_B      1536   // 4
#define OFF_SCLAST 1540   // 4     (includes mask[256])
#define OFF_CV     1544   // 128
#define OFF_VLAST  1672   // 128
#define OFF_XL     1800   // 128
#define OFF_VF     1928   // 256
#define OFF_UV     2304   // 256*128

__device__ inline float wave_sum(float v) {
#pragma unroll
    for (int off = 32; off >= 1; off >>= 1) v += __shfl_xor(v, off, 64);
    return v;
}
__device__ inline float wave_max(float v) {
#pragma unroll
    for (int off = 32; off >= 1; off >>= 1) v = fmaxf(v, __shfl_xor(v, off, 64));
    return v;
}
__device__ inline float gelu_exact(float x) {
    return 0.5f * x * (1.0f + erff(x * 0.7071067811865476f));
}

// ---------------- Kernel 1: single-block precompute ----------------
__global__ __launch_bounds__(256) void precompute_kernel(
    const float* __restrict__ A, const float* __restrict__ feat,
    const float* __restrict__ lab, const float* __restrict__ Wq,
    const float* __restrict__ bq, const float* __restrict__ Wk,
    const float* __restrict__ bk, const float* __restrict__ Wv,
    const float* __restrict__ bv, const float* __restrict__ g1,
    const float* __restrict__ beta1, float* __restrict__ ws)
{
    const int tid = threadIdx.x;
    __shared__ float red[256];
    __shared__ float smf[256];
    __shared__ float sxl[128];
    __shared__ float sQ[128], sK[128], sCK[128];
    __shared__ float swh[4][128];
    __shared__ float sc_cmax;

    // Phase A: cmax over |A| (257*257 elements)
    {
        float m = 0.f;
        for (int i = tid; i < SEQ * SEQ; i += 256) m = fmaxf(m, fabsf(A[i]));
        red[tid] = m;
        __syncthreads();
        for (int s = 128; s >= 1; s >>= 1) {
            if (tid < s) red[tid] = fmaxf(red[tid], red[tid + s]);
            __syncthreads();
        }
        if (tid == 0) sc_cmax = red[0];
        __syncthreads();
    }
    const float cmax = sc_cmax;

    // Phase B: dag mask row 256: cm[256,k] = |A[k,256]| (transpose), diag->1
    for (int k = tid; k < SEQ; k += 256) {
        float cmv;
        if (k == SEQ - 1) {
            cmv = 1.0f;
        } else {
            float v = fabsf(A[k * SEQ + (SEQ - 1)]);
            cmv = (cmax > 1e-6f) ? v / cmax : v + 1e-3f;
        }
        ws[OFF_MASK + k] = logf(cmv + 1e-9f);
    }
    __syncthreads();

    // Phase C: label LN (with g1,beta1 affine) -> xl
    {
        float lv = (tid < E) ? lab[tid] : 0.f;
        red[tid] = lv;
        __syncthreads();
        for (int s = 128; s >= 1; s >>= 1) { if (tid < s) red[tid] += red[tid + s]; __syncthreads(); }
        float lm = red[0] / (float)E;
        __syncthreads();
        float ld = (tid < E) ? (lv - lm) : 0.f;
        red[tid] = ld * ld;
        __syncthreads();
        for (int s = 128; s >= 1; s >>= 1) { if (tid < s) red[tid] += red[tid + s]; __syncthreads(); }
        float lrstd = rsqrtf(red[0] / (float)E + 1e-5f);
        __syncthreads();
        if (tid < E) {
            float x = ld * lrstd * g1[tid] + beta1[tid];
            sxl[tid] = x;
            ws[OFF_XL + tid] = x;
        }
    }

    // Phase D: per-feature-row mean/var of feat_emb
    {
        const int k = tid; // 256 threads == 256 rows
        float sum = 0.f;
        for (int e = 0; e < E; ++e) sum += feat[k * E + e];
        float mf = sum / (float)E;
        float ssq = 0.f;
        for (int e = 0; e < E; ++e) { float u = feat[k * E + e] - mf; ssq += u * u; }
        smf[k] = mf;
        ws[OFF_VF + k] = ssq / (float)E;
    }
    __syncthreads();

    // Phase E: Q_last / K_last ; V_last / cK ; cV
    {
        const int d = tid & 127, half = tid >> 7;
        {
            const float* W = half ? Wk : Wq;
            float acc = 0.f;
#pragma unroll 8
            for (int e = 0; e < E; ++e) acc += sxl[e] * W[e * E + d];
            acc += half ? bk[d] : bq[d];
            if (half) sK[d] = acc; else sQ[d] = acc;
        }
        if (half == 0) {
            float acc = 0.f;
#pragma unroll 8
            for (int e = 0; e < E; ++e) acc += sxl[e] * Wv[e * E + d];
            ws[OFF_VLAST + d] = acc + bv[d];
        } else {
            float acc = 0.f;
#pragma unroll 8
            for (int e = 0; e < E; ++e) acc += beta1[e] * Wk[e * E + d];
            sCK[d] = acc + bk[d];
        }
        if (half == 0) {
            float acc = 0.f;
#pragma unroll 8
            for (int e = 0; e < E; ++e) acc += beta1[e] * Wv[e * E + d];
            ws[OFF_CV + d] = acc + bv[d];
        }
    }
    __syncthreads();

    // Phase F: b_h and sc_last_h
    if (tid < NH) {
        const int h = tid;
        float bb = 0.f, sl = 0.f;
        for (int d = h * DK; d < (h + 1) * DK; ++d) {
            bb += sQ[d] * sCK[d];
            sl += sQ[d] * sK[d];
        }
        const float rs = 0.17677669529663687f; // 1/sqrt(32)
        ws[OFF_B + h] = bb * rs;
        ws[OFF_SCLAST + h] = sl * rs + ws[OFF_MASK + (SEQ - 1)];
    }

    // Phase G: w_h[e] = sum_{d in head h} Wk[e,d]*Q_last[d]
    {
        const int e = tid & 127;
        const int h0 = tid >> 7; // 0 or 1
        for (int h = h0; h < 4; h += 2) {
            float acc = 0.f;
#pragma unroll
            for (int d = h * DK; d < (h + 1) * DK; ++d) acc += Wk[e * E + d] * sQ[d];
            swh[h][e] = acc;
        }
    }
    __syncthreads();

    // Phase H: a[h,k] = (1/sqrt32) sum_e (feat[k,e]-mf_k)*g1[e]*swh[h][e]
    {
        const int k = tid;
        const float mf = smf[k];
        float a0 = 0.f, a1 = 0.f, a2 = 0.f, a3 = 0.f;
#pragma unroll 4
        for (int e = 0; e < E; ++e) {
            float u = (feat[k * E + e] - mf) * g1[e];
            a0 += u * swh[0][e];
            a1 += u * swh[1][e];
            a2 += u * swh[2][e];
            a3 += u * swh[3][e];
        }
        const float rs = 0.17677669529663687f;
        ws[OFF_A + k * 4 + 0] = a0 * rs;
        ws[OFF_A + k * 4 + 1] = a1 * rs;
        ws[OFF_A + k * 4 + 2] = a2 * rs;
        ws[OFF_A + k * 4 + 3] = a3 * rs;
    }
}

// ---------------- Kernel 2: UV[k,d] = sum_e (feat[k,e]-mf_k)*g1[e]*Wv[e,d] ----------------
__global__ __launch_bounds__(128) void uv_kernel(
    const float* __restrict__ feat, const float* __restrict__ g1,
    const float* __restrict__ Wv, float* __restrict__ ws)
{
    const int k = blockIdx.x, tid = threadIdx.x;
    __shared__ float su[128];
    __shared__ float red2[128];
    float f = feat[k * E + tid];
    red2[tid] = f;
    __syncthreads();
    for (int s = 64; s >= 1; s >>= 1) { if (tid < s) red2[tid] += red2[tid + s]; __syncthreads(); }
    float mf = red2[0] / (float)E;
    __syncthreads();
    su[tid] = (f - mf) * g1[tid];
    __syncthreads();
    float acc = 0.f;
#pragma unroll 8
    for (int e = 0; e < E; ++e) acc += su[e] * Wv[e * E + tid];
    ws[OFF_UV + k * E + tid] = acc;
}

// ---------------- Kernel 3: main, 4 samples per block ----------------
__global__ __launch_bounds__(256) void main_kernel(
    const float* __restrict__ Z, const float* __restrict__ Wo,
    const float* __restrict__ bo, const float* __restrict__ W1,
    const float* __restrict__ b1, const float* __restrict__ W2,
    const float* __restrict__ b2, const float* __restrict__ g2,
    const float* __restrict__ beta2, const float* __restrict__ alpha_p,
    const float* __restrict__ ws, float* __restrict__ out)
{
    const int tid = threadIdx.x;
    const int wv = tid >> 6, lane = tid & 63;
    const int n0 = blockIdx.x * 4;

    __shared__ float t[4][256];
    __shared__ float wm[4][4][256];
    __shared__ float sSumP[4][4], sP256[4][4], sInv[4][4];
    __shared__ float att[4][128];
    __shared__ float oar[4][128];
    __shared__ float h2[4][128];
    __shared__ float gg[4][256];

    // Phase 1: Z layernorm -> t values (wave = sample)
    {
        const int n = n0 + wv;
        float z[4];
#pragma unroll
        for (int i = 0; i < 4; ++i) z[i] = Z[n * F + lane + 64 * i];
        float sum = wave_sum(z[0] + z[1] + z[2] + z[3]);
        float mean = sum * (1.f / F);
        float ss = 0.f;
#pragma unroll
        for (int i = 0; i < 4; ++i) { float d = z[i] - mean; ss += d * d; }
        ss = wave_sum(ss);
        float rstd = rsqrtf(ss * (1.f / F) + 1e-5f);
#pragma unroll
        for (int i = 0; i < 4; ++i) {
            int k = lane + 64 * i;
            float s = (z[i] - mean) * rstd;
            float vf = ws[OFF_VF + k];
            t[wv][k] = s * rsqrtf(s * s * vf + 1e-5f);
        }
    }
    // same-wave LDS use only; no barrier needed before phase 2

    // Phase 2: scores + softmax per (sample=wave, head)
    {
        float tk[4], mk[4];
        float areg[4][4];
#pragma unroll
        for (int i = 0; i < 4; ++i) {
            int k = lane + 64 * i;
            tk[i] = t[wv][k];
            mk[i] = ws[OFF_MASK + k];
            float4 a4 = *(const float4*)(ws + OFF_A + k * 4);
            areg[i][0] = a4.x; areg[i][1] = a4.y; areg[i][2] = a4.z; areg[i][3] = a4.w;
        }
#pragma unroll
        for (int h = 0; h < 4; ++h) {
            float bh = ws[OFF_B + h];
            float scL = ws[OFF_SCLAST + h];
            float sc[4];
            float mx = -1e30f;
#pragma unroll
            for (int i = 0; i < 4; ++i) {
                sc[i] = tk[i] * areg[i][h] + bh + mk[i];
                mx = fmaxf(mx, sc[i]);
            }
            if (lane == 0) mx = fmaxf(mx, scL);
            mx = wave_max(mx);
            float local = 0.f;
            float p[4];
#pragma unroll
            for (int i = 0; i < 4; ++i) { p[i] = expf(sc[i] - mx); local += p[i]; }
            float sumP = wave_sum(local);
#pragma unroll
            for (int i = 0; i < 4; ++i) wm[wv][h][lane + 64 * i] = p[i] * tk[i];
            if (lane == 0) {
                float p256 = expf(scL - mx);
                sSumP[wv][h] = sumP;
                sP256[wv][h] = p256;
                sInv[wv][h] = 1.f / (sumP + p256);
            }
        }
    }
    __syncthreads();

    // Phase 3: attention combine: att[s][d] = (sum_k wm*UV + sumP*cV + p256*Vlast)/denom
    {
        const int d = tid & 127, sh = tid >> 7;
        const int s0 = sh * 2, s1 = sh * 2 + 1;
        const int h = d >> 5;
        float acc0 = 0.f, acc1 = 0.f;
#pragma unroll 8
        for (int k = 0; k < 256; ++k) {
            float uv = ws[OFF_UV + k * E + d];
            acc0 += wm[s0][h][k] * uv;
            acc1 += wm[s1][h][k] * uv;
        }
        float cv = ws[OFF_CV + d], vl = ws[OFF_VLAST + d];
        att[s0][d] = (acc0 + sSumP[s0][h] * cv + sP256[s0][h] * vl) * sInv[s0][h];
        att[s1][d] = (acc1 + sSumP[s1][h] * cv + sP256[s1][h] * vl) * sInv[s1][h];
    }
    __syncthreads();

    // Phase 4: o = att @ Wo + bo
    {
        const int d = tid & 127, sh = tid >> 7;
        const int s0 = sh * 2, s1 = sh * 2 + 1;
        float acc0 = 0.f, acc1 = 0.f;
#pragma unroll 8
        for (int e = 0; e < E; ++e) {
            float w = Wo[e * E + d];
            acc0 += att[s0][e] * w;
            acc1 += att[s1][e] * w;
        }
        float b = bo[d];
        oar[s0][d] = acc0 + b;
        oar[s1][d] = acc1 + b;
    }
    __syncthreads();

    // Phase 5: LN(o) with g2,beta2 (wave = sample)
    {
        float x0 = oar[wv][lane], x1 = oar[wv][lane + 64];
        float sum = wave_sum(x0 + x1);
        float mean = sum * (1.f / E);
        float d0 = x0 - mean, d1 = x1 - mean;
        float ss = wave_sum(d0 * d0 + d1 * d1);
        float rstd = rsqrtf(ss * (1.f / E) + 1e-5f);
        h2[wv][lane] = d0 * rstd * g2[lane] + beta2[lane];
        h2[wv][lane + 64] = d1 * rstd * g2[lane + 64] + beta2[lane + 64];
    }
    __syncthreads();

    // Phase 6: f1 = gelu(h2 @ W1 + b1), j = tid covers 256 outputs, all 4 samples
    {
        const int j = tid;
        float a0 = 0.f, a1 = 0.f, a2 = 0.f, a3 = 0.f;
#pragma unroll 4
        for (int d = 0; d < E; ++d) {
            float w = W1[d * (2 * E) + j];
            a0 += h2[0][d] * w;
            a1 += h2[1][d] * w;
            a2 += h2[2][d] * w;
            a3 += h2[3][d] * w;
        }
        float bb = b1[j];
        gg[0][j] = gelu_exact(a0 + bb);
        gg[1][j] = gelu_exact(a1 + bb);
        gg[2][j] = gelu_exact(a2 + bb);
        gg[3][j] = gelu_exact(a3 + bb);
    }
    __syncthreads();

    // Phase 7: f2 = gg @ W2 + b2 ; out = alpha*(o + f2) + xl
    {
        const int d = tid & 127, sh = tid >> 7;
        const int s0 = sh * 2, s1 = sh * 2 + 1;
        float acc0 = 0.f, acc1 = 0.f;
#pragma unroll 8
        for (int j = 0; j < 2 * E; ++j) {
            float w = W2[j * E + d];
            acc0 += gg[s0][j] * w;
            acc1 += gg[s1][j] * w;
        }
        float bb = b2[d];
        float xl = ws[OFF_XL + d];
        float alpha = alpha_p[0];
        out[(n0 + s0) * E + d] = alpha * (oar[s0][d] + acc0 + bb) + xl;
        out[(n0 + s1) * E + d] = alpha * (oar[s1][d] + acc1 + bb) + xl;
    }
}

extern "C" void kernel_launch(void* const* d_in, const int* in_sizes, int n_in,
                              void* d_out, int out_size, void* d_ws, size_t ws_size,
                              hipStream_t stream) {
    const float* Z     = (const float*)d_in[0];
    const float* A     = (const float*)d_in[1];
    const float* feat  = (const float*)d_in[2];
    const float* lab   = (const float*)d_in[3];
    const float* Wq    = (const float*)d_in[4];
    const float* bq    = (const float*)d_in[5];
    const float* Wk    = (const float*)d_in[6];
    const float* bk    = (const float*)d_in[7];
    const float* Wv    = (const float*)d_in[8];
    const float* bv    = (const float*)d_in[9];
    const float* Wo    = (const float*)d_in[10];
    const float* bo    = (const float*)d_in[11];
    const float* W1    = (const float*)d_in[12];
    const float* b1    = (const float*)d_in[13];
    const float* W2    = (const float*)d_in[14];
    const float* b2    = (const float*)d_in[15];
    const float* g1    = (const float*)d_in[16];
    const float* beta1 = (const float*)d_in[17];
    const float* g2    = (const float*)d_in[18];
    const float* beta2 = (const float*)d_in[19];
    const float* alpha = (const float*)d_in[20];
    float* ws = (float*)d_ws;
    float* out = (float*)d_out;

    hipLaunchKernelGGL(precompute_kernel, dim3(1), dim3(256), 0, stream,
                       A, feat, lab, Wq, bq, Wk, bk, Wv, bv, g1, beta1, ws);
    hipLaunchKernelGGL(uv_kernel, dim3(256), dim3(128), 0, stream,
                       feat, g1, Wv, ws);
    hipLaunchKernelGGL(main_kernel, dim3(NSAMP / 4), dim3(256), 0, stream,
                       Z, Wo, bo, W1, b1, W2, b2, g2, beta2, alpha, ws, out);
}

// Round 2
// 45.719 us; speedup vs baseline: 1.7488x; 1.7488x over previous
//
#include <hip/hip_runtime.h>
#include <hip/hip_bf16.h>
#include <math.h>

#define NSAMP 1024
#define F 256
#define E 128
#define SEQ 257
#define NH 4
#define DK 32

// ws float offsets
#define OFF_MASK   0      // 257
#define OFF_PMAX   264    // 128 partial |A| maxes
#define OFF_A      512    // 1024  a[k*4+h], already scaled by 1/sqrt(32)
#define OFF_B      1536   // 4
#define OFF_SCLAST 1540   // 4     (includes mask[256])
#define OFF_CV     1544   // 128
#define OFF_VLAST  1672   // 128
#define OFF_XL     1800   // 128
#define OFF_VF     1928   // 256
#define OFF_MF     2184   // 256
#define OFF_UV     2560   // 256*128 -> ends 35328
#define OFF_SQ     35328  // 128
#define OFF_SK     35456  // 128
#define OFF_SCK    35584  // 128
#define OFF_SWH    35712  // 4*128 -> ends 36224 (~145 KB total)

__device__ inline float wave_sum(float v) {
#pragma unroll
    for (int off = 32; off >= 1; off >>= 1) v += __shfl_xor(v, off, 64);
    return v;
}
__device__ inline float wave_max(float v) {
#pragma unroll
    for (int off = 32; off >= 1; off >>= 1) v = fmaxf(v, __shfl_xor(v, off, 64));
    return v;
}
__device__ inline float gelu_exact(float x) {
    return 0.5f * x * (1.0f + erff(x * 0.7071067811865476f));
}

// ---------------- pre1: 389 heterogeneous blocks, no cross-block deps ----------------
// blocks [0,128)   : partial abs-max of A -> ws[OFF_PMAX + bid]
// blocks [128,384) : feat_emb row (bid-128) mean/var -> OFF_MF / OFF_VF
// blocks [384,389) : 5 matvecs: j=0 Q_last, j=1 K_last, j=2 V_last, j=3 cK, j=4 cV
__global__ __launch_bounds__(128) void pre1_kernel(
    const float* __restrict__ A, const float* __restrict__ feat,
    const float* __restrict__ lab, const float* __restrict__ Wq,
    const float* __restrict__ bq, const float* __restrict__ Wk,
    const float* __restrict__ bk, const float* __restrict__ Wv,
    const float* __restrict__ bv, const float* __restrict__ g1,
    const float* __restrict__ beta1, float* __restrict__ ws)
{
    const int bid = blockIdx.x, tid = threadIdx.x;
    __shared__ float red[128];
    __shared__ float sv[128];

    if (bid < 128) {
        float m = 0.f;
        for (int i = bid * 128 + tid; i < SEQ * SEQ; i += 128 * 128)
            m = fmaxf(m, fabsf(A[i]));
        red[tid] = m;
        __syncthreads();
        for (int s = 64; s >= 1; s >>= 1) {
            if (tid < s) red[tid] = fmaxf(red[tid], red[tid + s]);
            __syncthreads();
        }
        if (tid == 0) ws[OFF_PMAX + bid] = red[0];
    } else if (bid < 384) {
        const int k = bid - 128;
        float f = feat[k * E + tid];
        red[tid] = f;
        __syncthreads();
        for (int s = 64; s >= 1; s >>= 1) { if (tid < s) red[tid] += red[tid + s]; __syncthreads(); }
        float mf = red[0] * (1.f / E);
        __syncthreads();
        float d = f - mf;
        red[tid] = d * d;
        __syncthreads();
        for (int s = 64; s >= 1; s >>= 1) { if (tid < s) red[tid] += red[tid + s]; __syncthreads(); }
        if (tid == 0) { ws[OFF_MF + k] = mf; ws[OFF_VF + k] = red[0] * (1.f / E); }
    } else {
        const int j = bid - 384;
        if (j < 3) {
            // label LN (redundant per block, cheap)
            float lv = lab[tid];
            red[tid] = lv;
            __syncthreads();
            for (int s = 64; s >= 1; s >>= 1) { if (tid < s) red[tid] += red[tid + s]; __syncthreads(); }
            float lm = red[0] * (1.f / E);
            __syncthreads();
            float d = lv - lm;
            red[tid] = d * d;
            __syncthreads();
            for (int s = 64; s >= 1; s >>= 1) { if (tid < s) red[tid] += red[tid + s]; __syncthreads(); }
            float rstd = rsqrtf(red[0] * (1.f / E) + 1e-5f);
            __syncthreads();
            float x = d * rstd * g1[tid] + beta1[tid];
            sv[tid] = x;
            if (j == 0) ws[OFF_XL + tid] = x;
        } else {
            sv[tid] = beta1[tid];
        }
        __syncthreads();
        const float* W    = (j == 0) ? Wq : (j == 2 || j == 4) ? Wv : Wk;
        const float* bias = (j == 0) ? bq : (j == 2 || j == 4) ? bv : bk;
        float acc = 0.f;
#pragma unroll 8
        for (int e = 0; e < E; ++e) acc += sv[e] * W[e * E + tid];
        acc += bias[tid];
        const int off = (j == 0) ? OFF_SQ : (j == 1) ? OFF_SK : (j == 2) ? OFF_VLAST
                      : (j == 3) ? OFF_SCK : OFF_CV;
        ws[off + tid] = acc;
    }
}

// ---------------- pre2: single small block: cmax finish, mask, b/scLast, swh ----------------
__global__ __launch_bounds__(256) void pre2_kernel(
    const float* __restrict__ A, const float* __restrict__ Wk,
    float* __restrict__ ws)
{
    const int tid = threadIdx.x;
    __shared__ float red[256];
    __shared__ float lQ[128], lK[128], lCK[128];
    __shared__ float scmax;

    float m = (tid < 128) ? ws[OFF_PMAX + tid] : 0.f;
    red[tid] = m;
    if (tid < 128) { lQ[tid] = ws[OFF_SQ + tid]; lK[tid] = ws[OFF_SK + tid]; lCK[tid] = ws[OFF_SCK + tid]; }
    __syncthreads();
    for (int s = 128; s >= 1; s >>= 1) {
        if (tid < s) red[tid] = fmaxf(red[tid], red[tid + s]);
        __syncthreads();
    }
    if (tid == 0) scmax = red[0];
    __syncthreads();
    const float cmax = scmax;

    // dag mask for k<256 (row 256 of cm = |A|^T)
    {
        const int k = tid;
        float v = fabsf(A[k * SEQ + (SEQ - 1)]);
        float cmv = (cmax > 1e-6f) ? v / cmax : v + 1e-3f;
        ws[OFF_MASK + k] = logf(cmv + 1e-9f);
    }

    // b_h, scLast (mask[256] term: diag->1 => log(1+1e-9))
    if (tid < NH) {
        const int h = tid;
        float bb = 0.f, sl = 0.f;
#pragma unroll
        for (int d = h * DK; d < (h + 1) * DK; ++d) { bb += lQ[d] * lCK[d]; sl += lQ[d] * lK[d]; }
        const float rs = 0.17677669529663687f;
        ws[OFF_B + h] = bb * rs;
        ws[OFF_SCLAST + h] = sl * rs + logf(1.0f + 1e-9f);
    }

    // swh[h][e] = sum_{d in head h} Wk[e,d] * Q_last[d]
    {
        const int e = tid & 127, h0 = tid >> 7;
        for (int h = h0; h < 4; h += 2) {
            float acc = 0.f;
#pragma unroll
            for (int d2 = 0; d2 < DK; ++d2) acc += Wk[e * E + h * DK + d2] * lQ[h * DK + d2];
            ws[OFF_SWH + h * E + e] = acc;
        }
    }
}

// ---------------- pre3: block k: a[h,k] + UV[k,:] ----------------
__global__ __launch_bounds__(128) void pre3_kernel(
    const float* __restrict__ feat, const float* __restrict__ g1,
    const float* __restrict__ Wv, float* __restrict__ ws)
{
    const int k = blockIdx.x, tid = threadIdx.x;
    __shared__ float su[128];
    __shared__ float sw[512];
    __shared__ float red[8];

    const float mf = ws[OFF_MF + k];
    const float s = (feat[k * E + tid] - mf) * g1[tid];
    su[tid] = s;
    sw[tid]       = ws[OFF_SWH + tid];
    sw[tid + 128] = ws[OFF_SWH + tid + 128];
    sw[tid + 256] = ws[OFF_SWH + tid + 256];
    sw[tid + 384] = ws[OFF_SWH + tid + 384];
    __syncthreads();

    const int wv = tid >> 6, lane = tid & 63;
#pragma unroll
    for (int h = 0; h < 4; ++h) {
        float v = s * sw[h * 128 + tid];
        v = wave_sum(v);
        if (lane == 0) red[h * 2 + wv] = v;
    }
    __syncthreads();
    if (tid < 4) ws[OFF_A + k * 4 + tid] = (red[tid * 2] + red[tid * 2 + 1]) * 0.17677669529663687f;

    float acc = 0.f;
#pragma unroll 8
    for (int e = 0; e < E; ++e) acc += su[e] * Wv[e * E + tid];
    ws[OFF_UV + k * E + tid] = acc;
}

// ---------------- main: 4 samples per block (unchanged) ----------------
__global__ __launch_bounds__(256) void main_kernel(
    const float* __restrict__ Z, const float* __restrict__ Wo,
    const float* __restrict__ bo, const float* __restrict__ W1,
    const float* __restrict__ b1, const float* __restrict__ W2,
    const float* __restrict__ b2, const float* __restrict__ g2,
    const float* __restrict__ beta2, const float* __restrict__ alpha_p,
    const float* __restrict__ ws, float* __restrict__ out)
{
    const int tid = threadIdx.x;
    const int wv = tid >> 6, lane = tid & 63;
    const int n0 = blockIdx.x * 4;

    __shared__ float t[4][256];
    __shared__ float wm[4][4][256];
    __shared__ float sSumP[4][4], sP256[4][4], sInv[4][4];
    __shared__ float att[4][128];
    __shared__ float oar[4][128];
    __shared__ float h2[4][128];
    __shared__ float gg[4][256];

    // Phase 1: Z layernorm -> t values (wave = sample)
    {
        const int n = n0 + wv;
        float z[4];
#pragma unroll
        for (int i = 0; i < 4; ++i) z[i] = Z[n * F + lane + 64 * i];
        float sum = wave_sum(z[0] + z[1] + z[2] + z[3]);
        float mean = sum * (1.f / F);
        float ss = 0.f;
#pragma unroll
        for (int i = 0; i < 4; ++i) { float d = z[i] - mean; ss += d * d; }
        ss = wave_sum(ss);
        float rstd = rsqrtf(ss * (1.f / F) + 1e-5f);
#pragma unroll
        for (int i = 0; i < 4; ++i) {
            int k = lane + 64 * i;
            float s = (z[i] - mean) * rstd;
            float vf = ws[OFF_VF + k];
            t[wv][k] = s * rsqrtf(s * s * vf + 1e-5f);
        }
    }
    // same-wave LDS use only; no barrier needed before phase 2

    // Phase 2: scores + softmax per (sample=wave, head)
    {
        float tk[4], mk[4];
        float areg[4][4];
#pragma unroll
        for (int i = 0; i < 4; ++i) {
            int k = lane + 64 * i;
            tk[i] = t[wv][k];
            mk[i] = ws[OFF_MASK + k];
            float4 a4 = *(const float4*)(ws + OFF_A + k * 4);
            areg[i][0] = a4.x; areg[i][1] = a4.y; areg[i][2] = a4.z; areg[i][3] = a4.w;
        }
#pragma unroll
        for (int h = 0; h < 4; ++h) {
            float bh = ws[OFF_B + h];
            float scL = ws[OFF_SCLAST + h];
            float sc[4];
            float mx = -1e30f;
#pragma unroll
            for (int i = 0; i < 4; ++i) {
                sc[i] = tk[i] * areg[i][h] + bh + mk[i];
                mx = fmaxf(mx, sc[i]);
            }
            if (lane == 0) mx = fmaxf(mx, scL);
            mx = wave_max(mx);
            float local = 0.f;
            float p[4];
#pragma unroll
            for (int i = 0; i < 4; ++i) { p[i] = expf(sc[i] - mx); local += p[i]; }
            float sumP = wave_sum(local);
#pragma unroll
            for (int i = 0; i < 4; ++i) wm[wv][h][lane + 64 * i] = p[i] * tk[i];
            if (lane == 0) {
                float p256 = expf(scL - mx);
                sSumP[wv][h] = sumP;
                sP256[wv][h] = p256;
                sInv[wv][h] = 1.f / (sumP + p256);
            }
        }
    }
    __syncthreads();

    // Phase 3: attention combine
    {
        const int d = tid & 127, sh = tid >> 7;
        const int s0 = sh * 2, s1 = sh * 2 + 1;
        const int h = d >> 5;
        float acc0 = 0.f, acc1 = 0.f;
#pragma unroll 8
        for (int k = 0; k < 256; ++k) {
            float uv = ws[OFF_UV + k * E + d];
            acc0 += wm[s0][h][k] * uv;
            acc1 += wm[s1][h][k] * uv;
        }
        float cv = ws[OFF_CV + d], vl = ws[OFF_VLAST + d];
        att[s0][d] = (acc0 + sSumP[s0][h] * cv + sP256[s0][h] * vl) * sInv[s0][h];
        att[s1][d] = (acc1 + sSumP[s1][h] * cv + sP256[s1][h] * vl) * sInv[s1][h];
    }
    __syncthreads();

    // Phase 4: o = att @ Wo + bo
    {
        const int d = tid & 127, sh = tid >> 7;
        const int s0 = sh * 2, s1 = sh * 2 + 1;
        float acc0 = 0.f, acc1 = 0.f;
#pragma unroll 8
        for (int e = 0; e < E; ++e) {
            float w = Wo[e * E + d];
            acc0 += att[s0][e] * w;
            acc1 += att[s1][e] * w;
        }
        float b = bo[d];
        oar[s0][d] = acc0 + b;
        oar[s1][d] = acc1 + b;
    }
    __syncthreads();

    // Phase 5: LN(o) with g2,beta2 (wave = sample)
    {
        float x0 = oar[wv][lane], x1 = oar[wv][lane + 64];
        float sum = wave_sum(x0 + x1);
        float mean = sum * (1.f / E);
        float d0 = x0 - mean, d1 = x1 - mean;
        float ss = wave_sum(d0 * d0 + d1 * d1);
        float rstd = rsqrtf(ss * (1.f / E) + 1e-5f);
        h2[wv][lane] = d0 * rstd * g2[lane] + beta2[lane];
        h2[wv][lane + 64] = d1 * rstd * g2[lane + 64] + beta2[lane + 64];
    }
    __syncthreads();

    // Phase 6: f1 = gelu(h2 @ W1 + b1)
    {
        const int j = tid;
        float a0 = 0.f, a1 = 0.f, a2 = 0.f, a3 = 0.f;
#pragma unroll 4
        for (int d = 0; d < E; ++d) {
            float w = W1[d * (2 * E) + j];
            a0 += h2[0][d] * w;
            a1 += h2[1][d] * w;
            a2 += h2[2][d] * w;
            a3 += h2[3][d] * w;
        }
        float bb = b1[j];
        gg[0][j] = gelu_exact(a0 + bb);
        gg[1][j] = gelu_exact(a1 + bb);
        gg[2][j] = gelu_exact(a2 + bb);
        gg[3][j] = gelu_exact(a3 + bb);
    }
    __syncthreads();

    // Phase 7: f2 = gg @ W2 + b2 ; out = alpha*(o + f2) + xl
    {
        const int d = tid & 127, sh = tid >> 7;
        const int s0 = sh * 2, s1 = sh * 2 + 1;
        float acc0 = 0.f, acc1 = 0.f;
#pragma unroll 8
        for (int j = 0; j < 2 * E; ++j) {
            float w = W2[j * E + d];
            acc0 += gg[s0][j] * w;
            acc1 += gg[s1][j] * w;
        }
        float bb = b2[d];
        float xl = ws[OFF_XL + d];
        float alpha = alpha_p[0];
        out[(n0 + s0) * E + d] = alpha * (oar[s0][d] + acc0 + bb) + xl;
        out[(n0 + s1) * E + d] = alpha * (oar[s1][d] + acc1 + bb) + xl;
    }
}

extern "C" void kernel_launch(void* const* d_in, const int* in_sizes, int n_in,
                              void* d_out, int out_size, void* d_ws, size_t ws_size,
                              hipStream_t stream) {
    const float* Z     = (const float*)d_in[0];
    const float* A     = (const float*)d_in[1];
    const float* feat  = (const float*)d_in[2];
    const float* lab   = (const float*)d_in[3];
    const float* Wq    = (const float*)d_in[4];
    const float* bq    = (const float*)d_in[5];
    const float* Wk    = (const float*)d_in[6];
    const float* bk    = (const float*)d_in[7];
    const float* Wv    = (const float*)d_in[8];
    const float* bv    = (const float*)d_in[9];
    const float* Wo    = (const float*)d_in[10];
    const float* bo    = (const float*)d_in[11];
    const float* W1    = (const float*)d_in[12];
    const float* b1    = (const float*)d_in[13];
    const float* W2    = (const float*)d_in[14];
    const float* b2    = (const float*)d_in[15];
    const float* g1    = (const float*)d_in[16];
    const float* beta1 = (const float*)d_in[17];
    const float* g2    = (const float*)d_in[18];
    const float* beta2 = (const float*)d_in[19];
    const float* alpha = (const float*)d_in[20];
    float* ws = (float*)d_ws;
    float* out = (float*)d_out;

    hipLaunchKernelGGL(pre1_kernel, dim3(389), dim3(128), 0, stream,
                       A, feat, lab, Wq, bq, Wk, bk, Wv, bv, g1, beta1, ws);
    hipLaunchKernelGGL(pre2_kernel, dim3(1), dim3(256), 0, stream, A, Wk, ws);
    hipLaunchKernelGGL(pre3_kernel, dim3(256), dim3(128), 0, stream, feat, g1, Wv, ws);
    hipLaunchKernelGGL(main_kernel, dim3(NSAMP / 4), dim3(256), 0, stream,
                       Z, Wo, bo, W1, b1, W2, b2, g2, beta2, alpha, ws, out);
}

// Round 3
// 32.165 us; speedup vs baseline: 2.4858x; 1.4214x over previous
//
#include <hip/hip_runtime.h>
#include <hip/hip_bf16.h>
#include <math.h>

#define NSAMP 1024
#define F 256
#define E 128
#define SEQ 257
#define NH 4
#define DK 32

// ws float offsets
#define OFF_MASK   0      // 257
#define OFF_PMAX   264    // 128 partial |A| maxes
#define OFF_A      512    // 1024  a[k*4+h], already scaled by 1/sqrt(32)
#define OFF_B      1536   // 4
#define OFF_SCLAST 1540   // 4     (includes mask[256])
#define OFF_CV     1544   // 128
#define OFF_VLAST  1672   // 128
#define OFF_XL     1800   // 128
#define OFF_VF     1928   // 256
#define OFF_MF     2184   // 256
#define OFF_UV     2560   // 256*128 -> ends 35328
#define OFF_SQ     35328  // 128
#define OFF_SK     35456  // 128
#define OFF_SCK    35584  // 128
#define OFF_SWH    35712  // 4*128 -> ends 36224 (~145 KB total)

__device__ inline float wave_sum(float v) {
#pragma unroll
    for (int off = 32; off >= 1; off >>= 1) v += __shfl_xor(v, off, 64);
    return v;
}
__device__ inline float wave_max(float v) {
#pragma unroll
    for (int off = 32; off >= 1; off >>= 1) v = fmaxf(v, __shfl_xor(v, off, 64));
    return v;
}
__device__ inline float gelu_exact(float x) {
    return 0.5f * x * (1.0f + erff(x * 0.7071067811865476f));
}

// ---------------- pre1: 389 heterogeneous blocks, no cross-block deps ----------------
__global__ __launch_bounds__(128) void pre1_kernel(
    const float* __restrict__ A, const float* __restrict__ feat,
    const float* __restrict__ lab, const float* __restrict__ Wq,
    const float* __restrict__ bq, const float* __restrict__ Wk,
    const float* __restrict__ bk, const float* __restrict__ Wv,
    const float* __restrict__ bv, const float* __restrict__ g1,
    const float* __restrict__ beta1, float* __restrict__ ws)
{
    const int bid = blockIdx.x, tid = threadIdx.x;
    __shared__ float red[128];
    __shared__ float sv[128];

    if (bid < 128) {
        float m = 0.f;
        for (int i = bid * 128 + tid; i < SEQ * SEQ; i += 128 * 128)
            m = fmaxf(m, fabsf(A[i]));
        red[tid] = m;
        __syncthreads();
        for (int s = 64; s >= 1; s >>= 1) {
            if (tid < s) red[tid] = fmaxf(red[tid], red[tid + s]);
            __syncthreads();
        }
        if (tid == 0) ws[OFF_PMAX + bid] = red[0];
    } else if (bid < 384) {
        const int k = bid - 128;
        float f = feat[k * E + tid];
        red[tid] = f;
        __syncthreads();
        for (int s = 64; s >= 1; s >>= 1) { if (tid < s) red[tid] += red[tid + s]; __syncthreads(); }
        float mf = red[0] * (1.f / E);
        __syncthreads();
        float d = f - mf;
        red[tid] = d * d;
        __syncthreads();
        for (int s = 64; s >= 1; s >>= 1) { if (tid < s) red[tid] += red[tid + s]; __syncthreads(); }
        if (tid == 0) { ws[OFF_MF + k] = mf; ws[OFF_VF + k] = red[0] * (1.f / E); }
    } else {
        const int j = bid - 384;
        if (j < 3) {
            float lv = lab[tid];
            red[tid] = lv;
            __syncthreads();
            for (int s = 64; s >= 1; s >>= 1) { if (tid < s) red[tid] += red[tid + s]; __syncthreads(); }
            float lm = red[0] * (1.f / E);
            __syncthreads();
            float d = lv - lm;
            red[tid] = d * d;
            __syncthreads();
            for (int s = 64; s >= 1; s >>= 1) { if (tid < s) red[tid] += red[tid + s]; __syncthreads(); }
            float rstd = rsqrtf(red[0] * (1.f / E) + 1e-5f);
            __syncthreads();
            float x = d * rstd * g1[tid] + beta1[tid];
            sv[tid] = x;
            if (j == 0) ws[OFF_XL + tid] = x;
        } else {
            sv[tid] = beta1[tid];
        }
        __syncthreads();
        const float* W    = (j == 0) ? Wq : (j == 2 || j == 4) ? Wv : Wk;
        const float* bias = (j == 0) ? bq : (j == 2 || j == 4) ? bv : bk;
        float acc = 0.f;
#pragma unroll 8
        for (int e = 0; e < E; ++e) acc += sv[e] * W[e * E + tid];
        acc += bias[tid];
        const int off = (j == 0) ? OFF_SQ : (j == 1) ? OFF_SK : (j == 2) ? OFF_VLAST
                      : (j == 3) ? OFF_SCK : OFF_CV;
        ws[off + tid] = acc;
    }
}

// ---------------- pre2: single small block ----------------
__global__ __launch_bounds__(256) void pre2_kernel(
    const float* __restrict__ A, const float* __restrict__ Wk,
    float* __restrict__ ws)
{
    const int tid = threadIdx.x;
    __shared__ float red[256];
    __shared__ float lQ[128], lK[128], lCK[128];
    __shared__ float scmax;

    float m = (tid < 128) ? ws[OFF_PMAX + tid] : 0.f;
    red[tid] = m;
    if (tid < 128) { lQ[tid] = ws[OFF_SQ + tid]; lK[tid] = ws[OFF_SK + tid]; lCK[tid] = ws[OFF_SCK + tid]; }
    __syncthreads();
    for (int s = 128; s >= 1; s >>= 1) {
        if (tid < s) red[tid] = fmaxf(red[tid], red[tid + s]);
        __syncthreads();
    }
    if (tid == 0) scmax = red[0];
    __syncthreads();
    const float cmax = scmax;

    {
        const int k = tid;
        float v = fabsf(A[k * SEQ + (SEQ - 1)]);
        float cmv = (cmax > 1e-6f) ? v / cmax : v + 1e-3f;
        ws[OFF_MASK + k] = logf(cmv + 1e-9f);
    }

    if (tid < NH) {
        const int h = tid;
        float bb = 0.f, sl = 0.f;
#pragma unroll
        for (int d = h * DK; d < (h + 1) * DK; ++d) { bb += lQ[d] * lCK[d]; sl += lQ[d] * lK[d]; }
        const float rs = 0.17677669529663687f;
        ws[OFF_B + h] = bb * rs;
        ws[OFF_SCLAST + h] = sl * rs + logf(1.0f + 1e-9f);
    }

    {
        const int e = tid & 127, h0 = tid >> 7;
        for (int h = h0; h < 4; h += 2) {
            float acc = 0.f;
#pragma unroll
            for (int d2 = 0; d2 < DK; ++d2) acc += Wk[e * E + h * DK + d2] * lQ[h * DK + d2];
            ws[OFF_SWH + h * E + e] = acc;
        }
    }
}

// ---------------- pre3: block k: a[h,k] + UV[k,:] ----------------
__global__ __launch_bounds__(128) void pre3_kernel(
    const float* __restrict__ feat, const float* __restrict__ g1,
    const float* __restrict__ Wv, float* __restrict__ ws)
{
    const int k = blockIdx.x, tid = threadIdx.x;
    __shared__ float su[128];
    __shared__ float sw[512];
    __shared__ float red[8];

    const float mf = ws[OFF_MF + k];
    const float s = (feat[k * E + tid] - mf) * g1[tid];
    su[tid] = s;
    sw[tid]       = ws[OFF_SWH + tid];
    sw[tid + 128] = ws[OFF_SWH + tid + 128];
    sw[tid + 256] = ws[OFF_SWH + tid + 256];
    sw[tid + 384] = ws[OFF_SWH + tid + 384];
    __syncthreads();

    const int wv = tid >> 6, lane = tid & 63;
#pragma unroll
    for (int h = 0; h < 4; ++h) {
        float v = s * sw[h * 128 + tid];
        v = wave_sum(v);
        if (lane == 0) red[h * 2 + wv] = v;
    }
    __syncthreads();
    if (tid < 4) ws[OFF_A + k * 4 + tid] = (red[tid * 2] + red[tid * 2 + 1]) * 0.17677669529663687f;

    float acc = 0.f;
#pragma unroll 8
    for (int e = 0; e < E; ++e) acc += su[e] * Wv[e * E + tid];
    ws[OFF_UV + k * E + tid] = acc;
}

// ---------------- main: 4 samples/block, 512 threads, split-K + LDS reduce ----------------
__global__ __launch_bounds__(512) void main_kernel(
    const float* __restrict__ Z, const float* __restrict__ Wo,
    const float* __restrict__ bo, const float* __restrict__ W1,
    const float* __restrict__ b1, const float* __restrict__ W2,
    const float* __restrict__ b2, const float* __restrict__ g2,
    const float* __restrict__ beta2, const float* __restrict__ alpha_p,
    const float* __restrict__ ws, float* __restrict__ out)
{
    const int tid = threadIdx.x;
    const int wv = tid >> 6, lane = tid & 63;
    const int n0 = blockIdx.x * 4;

    __shared__ float wm4[4][256][4];   // [h][k][s]  16 KB
    __shared__ float att4[128][4];     // [e][s]
    __shared__ float oar[4][128];      // [s][d]
    __shared__ float h24[128][4];      // [d][s]
    __shared__ float gg4[256][4];      // [j][s]
    __shared__ float red[2048];        // partials, 8 KB, multi-layout
    __shared__ float sSumP[4][4], sP256[4][4], sInv[4][4]; // [sample][head]

    // ---- Phase 1+2: Z-LN + scores + softmax, wave = sample (waves 0-3) ----
    if (wv < 4) {
        const int n = n0 + wv;
        float z[4];
#pragma unroll
        for (int i = 0; i < 4; ++i) z[i] = Z[n * F + lane + 64 * i];
        float sum = wave_sum(z[0] + z[1] + z[2] + z[3]);
        float mean = sum * (1.f / F);
        float ss = 0.f;
#pragma unroll
        for (int i = 0; i < 4; ++i) { float d = z[i] - mean; ss += d * d; }
        ss = wave_sum(ss);
        float rstd = rsqrtf(ss * (1.f / F) + 1e-5f);

        float tk[4], mk[4], areg[4][4];
#pragma unroll
        for (int i = 0; i < 4; ++i) {
            int k = lane + 64 * i;
            float s = (z[i] - mean) * rstd;
            float vf = ws[OFF_VF + k];
            tk[i] = s * rsqrtf(s * s * vf + 1e-5f);
            mk[i] = ws[OFF_MASK + k];
            float4 a4 = *(const float4*)(ws + OFF_A + k * 4);
            areg[i][0] = a4.x; areg[i][1] = a4.y; areg[i][2] = a4.z; areg[i][3] = a4.w;
        }
#pragma unroll
        for (int h = 0; h < 4; ++h) {
            float bh = ws[OFF_B + h];
            float scL = ws[OFF_SCLAST + h];
            float sc[4];
            float mx = -1e30f;
#pragma unroll
            for (int i = 0; i < 4; ++i) {
                sc[i] = tk[i] * areg[i][h] + bh + mk[i];
                mx = fmaxf(mx, sc[i]);
            }
            if (lane == 0) mx = fmaxf(mx, scL);
            mx = wave_max(mx);
            float local = 0.f;
            float p[4];
#pragma unroll
            for (int i = 0; i < 4; ++i) { p[i] = expf(sc[i] - mx); local += p[i]; }
            float sumP = wave_sum(local);
#pragma unroll
            for (int i = 0; i < 4; ++i) wm4[h][lane + 64 * i][wv] = p[i] * tk[i];
            if (lane == 0) {
                float p256 = expf(scL - mx);
                sSumP[wv][h] = sumP;
                sP256[wv][h] = p256;
                sInv[wv][h] = 1.f / (sumP + p256);
            }
        }
    }
    __syncthreads();

    const int g = tid >> 7;      // 0..3 split group
    const int d = tid & 127;

    // ---- Phase 3: attention combine, k split 4 ways ----
    {
        const int h = d >> 5;
        float a0 = 0.f, a1 = 0.f, a2 = 0.f, a3 = 0.f;
        const float* uvp = ws + OFF_UV + (g * 64) * E + d;
#pragma unroll 8
        for (int kk = 0; kk < 64; ++kk) {
            float uv = uvp[kk * E];
            float4 w = *(const float4*)&wm4[h][g * 64 + kk][0];
            a0 += w.x * uv; a1 += w.y * uv; a2 += w.z * uv; a3 += w.w * uv;
        }
        float* r = red + g * 512 + d;   // red[g][s][d]
        r[0] = a0; r[128] = a1; r[256] = a2; r[384] = a3;
    }
    __syncthreads();
    {
        const int s = tid >> 7, dd = tid & 127, hh = dd >> 5;
        float v = red[s * 128 + dd] + red[512 + s * 128 + dd]
                + red[1024 + s * 128 + dd] + red[1536 + s * 128 + dd];
        float cv = ws[OFF_CV + dd], vl = ws[OFF_VLAST + dd];
        att4[dd][s] = (v + sSumP[s][hh] * cv + sP256[s][hh] * vl) * sInv[s][hh];
    }
    __syncthreads();

    // ---- Phase 4: o = att @ Wo, e split 4 ways ----
    {
        float a0 = 0.f, a1 = 0.f, a2 = 0.f, a3 = 0.f;
        const float* wop = Wo + (g * 32) * E + d;
#pragma unroll 8
        for (int i = 0; i < 32; ++i) {
            float w = wop[i * E];
            float4 av = *(const float4*)&att4[g * 32 + i][0];
            a0 += av.x * w; a1 += av.y * w; a2 += av.z * w; a3 += av.w * w;
        }
        float* r = red + g * 512 + d;
        r[0] = a0; r[128] = a1; r[256] = a2; r[384] = a3;
    }
    __syncthreads();
    {
        const int s = tid >> 7, dd = tid & 127;
        float v = red[s * 128 + dd] + red[512 + s * 128 + dd]
                + red[1024 + s * 128 + dd] + red[1536 + s * 128 + dd];
        oar[s][dd] = v + bo[dd];
    }
    __syncthreads();

    // ---- Phase 5: LN(o) with g2,beta2 (wave = sample) ----
    if (wv < 4) {
        float x0 = oar[wv][lane], x1 = oar[wv][lane + 64];
        float sum = wave_sum(x0 + x1);
        float mean = sum * (1.f / E);
        float d0 = x0 - mean, d1 = x1 - mean;
        float ss = wave_sum(d0 * d0 + d1 * d1);
        float rstd = rsqrtf(ss * (1.f / E) + 1e-5f);
        h24[lane][wv]      = d0 * rstd * g2[lane] + beta2[lane];
        h24[lane + 64][wv] = d1 * rstd * g2[lane + 64] + beta2[lane + 64];
    }
    __syncthreads();

    // ---- Phase 6: f1 = gelu(h2 @ W1 + b1), d split 2 ways ----
    {
        const int grp = tid >> 8;       // 0/1
        const int j = tid & 255;
        float a0 = 0.f, a1 = 0.f, a2 = 0.f, a3 = 0.f;
        const float* w1p = W1 + (grp * 64) * (2 * E) + j;
#pragma unroll 8
        for (int i = 0; i < 64; ++i) {
            float w = w1p[i * (2 * E)];
            float4 hv = *(const float4*)&h24[grp * 64 + i][0];
            a0 += hv.x * w; a1 += hv.y * w; a2 += hv.z * w; a3 += hv.w * w;
        }
        float* r = red + grp * 1024 + j;   // red[grp][s][j]
        r[0] = a0; r[256] = a1; r[512] = a2; r[768] = a3;
    }
    __syncthreads();
    {
        const int s2 = tid >> 8, j = tid & 255;
#pragma unroll
        for (int q = 0; q < 2; ++q) {
            int s = 2 * s2 + q;
            float v = red[s * 256 + j] + red[1024 + s * 256 + j] + b1[j];
            gg4[j][s] = gelu_exact(v);
        }
    }
    __syncthreads();

    // ---- Phase 7: f2 = gg @ W2 + b2; out = alpha*(o+f2)+xl, j split 4 ways ----
    {
        float a0 = 0.f, a1 = 0.f, a2 = 0.f, a3 = 0.f;
        const float* w2p = W2 + (g * 64) * E + d;
#pragma unroll 8
        for (int i = 0; i < 64; ++i) {
            float w = w2p[i * E];
            float4 gv = *(const float4*)&gg4[g * 64 + i][0];
            a0 += gv.x * w; a1 += gv.y * w; a2 += gv.z * w; a3 += gv.w * w;
        }
        float* r = red + g * 512 + d;
        r[0] = a0; r[128] = a1; r[256] = a2; r[384] = a3;
    }
    __syncthreads();
    {
        const int s = tid >> 7, dd = tid & 127;
        float f2 = red[s * 128 + dd] + red[512 + s * 128 + dd]
                 + red[1024 + s * 128 + dd] + red[1536 + s * 128 + dd] + b2[dd];
        float xl = ws[OFF_XL + dd];
        float alpha = alpha_p[0];
        out[(n0 + s) * E + dd] = alpha * (oar[s][dd] + f2) + xl;
    }
}

extern "C" void kernel_launch(void* const* d_in, const int* in_sizes, int n_in,
                              void* d_out, int out_size, void* d_ws, size_t ws_size,
                              hipStream_t stream) {
    const float* Z     = (const float*)d_in[0];
    const float* A     = (const float*)d_in[1];
    const float* feat  = (const float*)d_in[2];
    const float* lab   = (const float*)d_in[3];
    const float* Wq    = (const float*)d_in[4];
    const float* bq    = (const float*)d_in[5];
    const float* Wk    = (const float*)d_in[6];
    const float* bk    = (const float*)d_in[7];
    const float* Wv    = (const float*)d_in[8];
    const float* bv    = (const float*)d_in[9];
    const float* Wo    = (const float*)d_in[10];
    const float* bo    = (const float*)d_in[11];
    const float* W1    = (const float*)d_in[12];
    const float* b1    = (const float*)d_in[13];
    const float* W2    = (const float*)d_in[14];
    const float* b2    = (const float*)d_in[15];
    const float* g1    = (const float*)d_in[16];
    const float* beta1 = (const float*)d_in[17];
    const float* g2    = (const float*)d_in[18];
    const float* beta2 = (const float*)d_in[19];
    const float* alpha = (const float*)d_in[20];
    float* ws = (float*)d_ws;
    float* out = (float*)d_out;

    hipLaunchKernelGGL(pre1_kernel, dim3(389), dim3(128), 0, stream,
                       A, feat, lab, Wq, bq, Wk, bk, Wv, bv, g1, beta1, ws);
    hipLaunchKernelGGL(pre2_kernel, dim3(1), dim3(256), 0, stream, A, Wk, ws);
    hipLaunchKernelGGL(pre3_kernel, dim3(256), dim3(128), 0, stream, feat, g1, Wv, ws);
    hipLaunchKernelGGL(main_kernel, dim3(NSAMP / 4), dim3(512), 0, stream,
                       Z, Wo, bo, W1, b1, W2, b2, g2, beta2, alpha, ws, out);
}

// Round 4
// 25.771 us; speedup vs baseline: 3.1025x; 1.2481x over previous
//
#include <hip/hip_runtime.h>
#include <hip/hip_bf16.h>
#include <math.h>

#define NSAMP 1024
#define F 256
#define E 128
#define SEQ 257
#define NH 4
#define DK 32

// ws float offsets
#define OFF_MASK   0      // 257 (only k<256 used downstream)
#define OFF_PMAX   264    // 128 partial |A| maxes
#define OFF_A      512    // 1024  a[k*4+h], already scaled by 1/sqrt(32)
#define OFF_B      1536   // 4
#define OFF_SCLAST 1540   // 4
#define OFF_CV     1544   // 128
#define OFF_VLAST  1672   // 128
#define OFF_XL     1800   // 128
#define OFF_VF     1928   // 256
#define OFF_MF     2184   // 256
#define OFF_UV     2560   // 256*128 -> ends 35328
#define OFF_SQ     35328  // 128
#define OFF_SK     35456  // 128
#define OFF_SCK    35584  // 128

__device__ inline float wave_sum(float v) {
#pragma unroll
    for (int off = 32; off >= 1; off >>= 1) v += __shfl_xor(v, off, 64);
    return v;
}
__device__ inline float wave_max(float v) {
#pragma unroll
    for (int off = 32; off >= 1; off >>= 1) v = fmaxf(v, __shfl_xor(v, off, 64));
    return v;
}
__device__ inline float gelu_exact(float x) {
    return 0.5f * x * (1.0f + erff(x * 0.7071067811865476f));
}

// ---------------- pre1: 389 heterogeneous blocks, no cross-block deps ----------------
__global__ __launch_bounds__(128) void pre1_kernel(
    const float* __restrict__ A, const float* __restrict__ feat,
    const float* __restrict__ lab, const float* __restrict__ Wq,
    const float* __restrict__ bq, const float* __restrict__ Wk,
    const float* __restrict__ bk, const float* __restrict__ Wv,
    const float* __restrict__ bv, const float* __restrict__ g1,
    const float* __restrict__ beta1, float* __restrict__ ws)
{
    const int bid = blockIdx.x, tid = threadIdx.x;
    __shared__ float red[128];
    __shared__ float sv[128];

    if (bid < 128) {
        float m = 0.f;
        for (int i = bid * 128 + tid; i < SEQ * SEQ; i += 128 * 128)
            m = fmaxf(m, fabsf(A[i]));
        red[tid] = m;
        __syncthreads();
        for (int s = 64; s >= 1; s >>= 1) {
            if (tid < s) red[tid] = fmaxf(red[tid], red[tid + s]);
            __syncthreads();
        }
        if (tid == 0) ws[OFF_PMAX + bid] = red[0];
    } else if (bid < 384) {
        const int k = bid - 128;
        float f = feat[k * E + tid];
        red[tid] = f;
        __syncthreads();
        for (int s = 64; s >= 1; s >>= 1) { if (tid < s) red[tid] += red[tid + s]; __syncthreads(); }
        float mf = red[0] * (1.f / E);
        __syncthreads();
        float d = f - mf;
        red[tid] = d * d;
        __syncthreads();
        for (int s = 64; s >= 1; s >>= 1) { if (tid < s) red[tid] += red[tid + s]; __syncthreads(); }
        if (tid == 0) { ws[OFF_MF + k] = mf; ws[OFF_VF + k] = red[0] * (1.f / E); }
    } else {
        const int j = bid - 384;
        if (j < 3) {
            float lv = lab[tid];
            red[tid] = lv;
            __syncthreads();
            for (int s = 64; s >= 1; s >>= 1) { if (tid < s) red[tid] += red[tid + s]; __syncthreads(); }
            float lm = red[0] * (1.f / E);
            __syncthreads();
            float d = lv - lm;
            red[tid] = d * d;
            __syncthreads();
            for (int s = 64; s >= 1; s >>= 1) { if (tid < s) red[tid] += red[tid + s]; __syncthreads(); }
            float rstd = rsqrtf(red[0] * (1.f / E) + 1e-5f);
            __syncthreads();
            float x = d * rstd * g1[tid] + beta1[tid];
            sv[tid] = x;
            if (j == 0) ws[OFF_XL + tid] = x;
        } else {
            sv[tid] = beta1[tid];
        }
        __syncthreads();
        const float* W    = (j == 0) ? Wq : (j == 2 || j == 4) ? Wv : Wk;
        const float* bias = (j == 0) ? bq : (j == 2 || j == 4) ? bv : bk;
        float acc = 0.f;
#pragma unroll 8
        for (int e = 0; e < E; ++e) acc += sv[e] * W[e * E + tid];
        acc += bias[tid];
        const int off = (j == 0) ? OFF_SQ : (j == 1) ? OFF_SK : (j == 2) ? OFF_VLAST
                      : (j == 3) ? OFF_SCK : OFF_CV;
        ws[off + tid] = acc;
    }
}

// ---------------- pre23: 257 blocks x 256 threads ----------------
// blocks [0,256): UV[k,:] + UK[k,:] -> a[h,k]   (swh eliminated algebraically)
// block 256     : cmax finish, mask, b_h, scLast
__global__ __launch_bounds__(256) void pre23_kernel(
    const float* __restrict__ A, const float* __restrict__ feat,
    const float* __restrict__ g1, const float* __restrict__ Wk,
    const float* __restrict__ Wv, float* __restrict__ ws)
{
    const int bid = blockIdx.x, tid = threadIdx.x;
    __shared__ float su[128];
    __shared__ float sUK[128];
    __shared__ float red[256];

    if (bid < 256) {
        const int k = bid;
        if (tid < 128) {
            const float mf = ws[OFF_MF + k];
            su[tid] = (feat[k * E + tid] - mf) * g1[tid];
        }
        __syncthreads();
        {
            const int d = tid & 127;
            const float* W = (tid < 128) ? Wv : Wk;
            float acc = 0.f;
#pragma unroll 8
            for (int e = 0; e < E; ++e) acc += su[e] * W[e * E + d];
            if (tid < 128) ws[OFF_UV + k * E + d] = acc;
            else sUK[d] = acc;
        }
        __syncthreads();
        if (tid < 128) {
            float v = sUK[tid] * ws[OFF_SQ + tid];
            // reduce within 32-lane head group
#pragma unroll
            for (int off = 16; off >= 1; off >>= 1) v += __shfl_xor(v, off, 64);
            if ((tid & 31) == 0)
                ws[OFF_A + k * 4 + (tid >> 5)] = v * 0.17677669529663687f;
        }
    } else {
        // finish cmax
        float m = (tid < 128) ? ws[OFF_PMAX + tid] : 0.f;
        red[tid] = m;
        __syncthreads();
        for (int s = 128; s >= 1; s >>= 1) {
            if (tid < s) red[tid] = fmaxf(red[tid], red[tid + s]);
            __syncthreads();
        }
        const float cmax = red[0];
        // mask for k<256
        {
            float v = fabsf(A[tid * SEQ + (SEQ - 1)]);
            float cmv = (cmax > 1e-6f) ? v / cmax : v + 1e-3f;
            ws[OFF_MASK + tid] = logf(cmv + 1e-9f);
        }
        // stage Q/K/cK in LDS (reuse su/sUK/red)
        if (tid < 128) su[tid]  = ws[OFF_SQ + tid];
        else           sUK[tid - 128] = ws[OFF_SK + tid - 128];
        if (tid < 128) red[tid] = ws[OFF_SCK + tid];
        __syncthreads();
        if (tid < NH) {
            const int h = tid;
            float bb = 0.f, sl = 0.f;
#pragma unroll
            for (int d = h * DK; d < (h + 1) * DK; ++d) {
                bb += su[d] * red[d];
                sl += su[d] * sUK[d];
            }
            const float rs = 0.17677669529663687f;
            ws[OFF_B + h] = bb * rs;
            ws[OFF_SCLAST + h] = sl * rs + logf(1.0f + 1e-9f);
        }
    }
}

// ---------------- main: 4 samples/block, 1024 threads, split-K 8 ----------------
__global__ __launch_bounds__(1024) void main_kernel(
    const float* __restrict__ Z, const float* __restrict__ Wo,
    const float* __restrict__ bo, const float* __restrict__ W1,
    const float* __restrict__ b1, const float* __restrict__ W2,
    const float* __restrict__ b2, const float* __restrict__ g2,
    const float* __restrict__ beta2, const float* __restrict__ alpha_p,
    const float* __restrict__ ws, float* __restrict__ out)
{
    const int tid = threadIdx.x;
    const int wv = tid >> 6, lane = tid & 63;
    const int n0 = blockIdx.x * 4;

    __shared__ float wm4[4][256][4];   // [h][k][s]  16 KB
    __shared__ float att4[128][4];
    __shared__ float oar[4][128];
    __shared__ float h24[128][4];
    __shared__ float gg4[256][4];
    __shared__ float red[4096];        // 16 KB partials
    __shared__ float sSumP[4][4], sP256[4][4], sInv[4][4];

    // ---- Phase 1+2: Z-LN + scores + softmax (waves 0-3, wave = sample) ----
    if (wv < 4) {
        const int n = n0 + wv;
        float z[4];
#pragma unroll
        for (int i = 0; i < 4; ++i) z[i] = Z[n * F + lane + 64 * i];
        float sum = wave_sum(z[0] + z[1] + z[2] + z[3]);
        float mean = sum * (1.f / F);
        float ss = 0.f;
#pragma unroll
        for (int i = 0; i < 4; ++i) { float d = z[i] - mean; ss += d * d; }
        ss = wave_sum(ss);
        float rstd = rsqrtf(ss * (1.f / F) + 1e-5f);

        float tk[4], mk[4], areg[4][4];
#pragma unroll
        for (int i = 0; i < 4; ++i) {
            int k = lane + 64 * i;
            float s = (z[i] - mean) * rstd;
            float vf = ws[OFF_VF + k];
            tk[i] = s * rsqrtf(s * s * vf + 1e-5f);
            mk[i] = ws[OFF_MASK + k];
            float4 a4 = *(const float4*)(ws + OFF_A + k * 4);
            areg[i][0] = a4.x; areg[i][1] = a4.y; areg[i][2] = a4.z; areg[i][3] = a4.w;
        }
#pragma unroll
        for (int h = 0; h < 4; ++h) {
            float bh = ws[OFF_B + h];
            float scL = ws[OFF_SCLAST + h];
            float sc[4];
            float mx = -1e30f;
#pragma unroll
            for (int i = 0; i < 4; ++i) {
                sc[i] = tk[i] * areg[i][h] + bh + mk[i];
                mx = fmaxf(mx, sc[i]);
            }
            if (lane == 0) mx = fmaxf(mx, scL);
            mx = wave_max(mx);
            float local = 0.f;
            float p[4];
#pragma unroll
            for (int i = 0; i < 4; ++i) { p[i] = expf(sc[i] - mx); local += p[i]; }
            float sumP = wave_sum(local);
#pragma unroll
            for (int i = 0; i < 4; ++i) wm4[h][lane + 64 * i][wv] = p[i] * tk[i];
            if (lane == 0) {
                float p256 = expf(scL - mx);
                sSumP[wv][h] = sumP;
                sP256[wv][h] = p256;
                sInv[wv][h] = 1.f / (sumP + p256);
            }
        }
    }
    __syncthreads();

    const int g = tid >> 7;      // 0..7 split group
    const int d = tid & 127;

    // ---- Phase 3: attention combine, k split 8 ways (32 iters) ----
    {
        const int h = d >> 5;
        float a0 = 0.f, a1 = 0.f, a2 = 0.f, a3 = 0.f;
        const float* uvp = ws + OFF_UV + (g * 32) * E + d;
#pragma unroll 8
        for (int kk = 0; kk < 32; ++kk) {
            float uv = uvp[kk * E];
            float4 w = *(const float4*)&wm4[h][g * 32 + kk][0];
            a0 += w.x * uv; a1 += w.y * uv; a2 += w.z * uv; a3 += w.w * uv;
        }
        float* r = red + g * 512 + d;   // red[g][s][d]
        r[0] = a0; r[128] = a1; r[256] = a2; r[384] = a3;
    }
    __syncthreads();
    if (tid < 512) {
        const int s = tid >> 7, dd = tid & 127, hh = dd >> 5;
        float v = 0.f;
#pragma unroll
        for (int gi = 0; gi < 8; ++gi) v += red[gi * 512 + s * 128 + dd];
        float cv = ws[OFF_CV + dd], vl = ws[OFF_VLAST + dd];
        att4[dd][s] = (v + sSumP[s][hh] * cv + sP256[s][hh] * vl) * sInv[s][hh];
    }
    __syncthreads();

    // ---- Phase 4: o = att @ Wo, e split 8 ways (16 iters) ----
    {
        float a0 = 0.f, a1 = 0.f, a2 = 0.f, a3 = 0.f;
        const float* wop = Wo + (g * 16) * E + d;
#pragma unroll 8
        for (int i = 0; i < 16; ++i) {
            float w = wop[i * E];
            float4 av = *(const float4*)&att4[g * 16 + i][0];
            a0 += av.x * w; a1 += av.y * w; a2 += av.z * w; a3 += av.w * w;
        }
        float* r = red + g * 512 + d;
        r[0] = a0; r[128] = a1; r[256] = a2; r[384] = a3;
    }
    __syncthreads();
    if (tid < 512) {
        const int s = tid >> 7, dd = tid & 127;
        float v = 0.f;
#pragma unroll
        for (int gi = 0; gi < 8; ++gi) v += red[gi * 512 + s * 128 + dd];
        oar[s][dd] = v + bo[dd];
    }
    __syncthreads();

    // ---- Phase 5: LN(o) with g2,beta2 (waves 0-3) ----
    if (wv < 4) {
        float x0 = oar[wv][lane], x1 = oar[wv][lane + 64];
        float sum = wave_sum(x0 + x1);
        float mean = sum * (1.f / E);
        float d0 = x0 - mean, d1 = x1 - mean;
        float ss = wave_sum(d0 * d0 + d1 * d1);
        float rstd = rsqrtf(ss * (1.f / E) + 1e-5f);
        h24[lane][wv]      = d0 * rstd * g2[lane] + beta2[lane];
        h24[lane + 64][wv] = d1 * rstd * g2[lane + 64] + beta2[lane + 64];
    }
    __syncthreads();

    // ---- Phase 6: f1 = gelu(h2 @ W1 + b1), d split 4 ways (32 iters) ----
    {
        const int grp = tid >> 8;       // 0..3
        const int j = tid & 255;
        float a0 = 0.f, a1 = 0.f, a2 = 0.f, a3 = 0.f;
        const float* w1p = W1 + (grp * 32) * (2 * E) + j;
#pragma unroll 8
        for (int i = 0; i < 32; ++i) {
            float w = w1p[i * (2 * E)];
            float4 hv = *(const float4*)&h24[grp * 32 + i][0];
            a0 += hv.x * w; a1 += hv.y * w; a2 += hv.z * w; a3 += hv.w * w;
        }
        float* r = red + grp * 1024 + j;   // red[grp][s][j]
        r[0] = a0; r[256] = a1; r[512] = a2; r[768] = a3;
    }
    __syncthreads();
    {
        const int s = tid >> 8, j = tid & 255;
        float v = red[s * 256 + j] + red[1024 + s * 256 + j]
                + red[2048 + s * 256 + j] + red[3072 + s * 256 + j] + b1[j];
        gg4[j][s] = gelu_exact(v);
    }
    __syncthreads();

    // ---- Phase 7: f2 = gg @ W2 + b2; out, j split 8 ways (32 iters) ----
    {
        float a0 = 0.f, a1 = 0.f, a2 = 0.f, a3 = 0.f;
        const float* w2p = W2 + (g * 32) * E + d;
#pragma unroll 8
        for (int i = 0; i < 32; ++i) {
            float w = w2p[i * E];
            float4 gv = *(const float4*)&gg4[g * 32 + i][0];
            a0 += gv.x * w; a1 += gv.y * w; a2 += gv.z * w; a3 += gv.w * w;
        }
        float* r = red + g * 512 + d;
        r[0] = a0; r[128] = a1; r[256] = a2; r[384] = a3;
    }
    __syncthreads();
    if (tid < 512) {
        const int s = tid >> 7, dd = tid & 127;
        float f2 = b2[dd];
#pragma unroll
        for (int gi = 0; gi < 8; ++gi) f2 += red[gi * 512 + s * 128 + dd];
        float xl = ws[OFF_XL + dd];
        float alpha = alpha_p[0];
        out[(n0 + s) * E + dd] = alpha * (oar[s][dd] + f2) + xl;
    }
}

extern "C" void kernel_launch(void* const* d_in, const int* in_sizes, int n_in,
                              void* d_out, int out_size, void* d_ws, size_t ws_size,
                              hipStream_t stream) {
    const float* Z     = (const float*)d_in[0];
    const float* A     = (const float*)d_in[1];
    const float* feat  = (const float*)d_in[2];
    const float* lab   = (const float*)d_in[3];
    const float* Wq    = (const float*)d_in[4];
    const float* bq    = (const float*)d_in[5];
    const float* Wk    = (const float*)d_in[6];
    const float* bk    = (const float*)d_in[7];
    const float* Wv    = (const float*)d_in[8];
    const float* bv    = (const float*)d_in[9];
    const float* Wo    = (const float*)d_in[10];
    const float* bo    = (const float*)d_in[11];
    const float* W1    = (const float*)d_in[12];
    const float* b1    = (const float*)d_in[13];
    const float* W2    = (const float*)d_in[14];
    const float* b2    = (const float*)d_in[15];
    const float* g1    = (const float*)d_in[16];
    const float* beta1 = (const float*)d_in[17];
    const float* g2    = (const float*)d_in[18];
    const float* beta2 = (const float*)d_in[19];
    const float* alpha = (const float*)d_in[20];
    float* ws = (float*)d_ws;
    float* out = (float*)d_out;

    hipLaunchKernelGGL(pre1_kernel, dim3(389), dim3(128), 0, stream,
                       A, feat, lab, Wq, bq, Wk, bk, Wv, bv, g1, beta1, ws);
    hipLaunchKernelGGL(pre23_kernel, dim3(257), dim3(256), 0, stream,
                       A, feat, g1, Wk, Wv, ws);
    hipLaunchKernelGGL(main_kernel, dim3(NSAMP / 4), dim3(1024), 0, stream,
                       Z, Wo, bo, W1, b1, W2, b2, g2, beta2, alpha, ws, out);
}